// Round 1
// baseline (845.082 us; speedup 1.0000x reference)
//
#include <hip/hip_runtime.h>
#include <hip/hip_bf16.h>

// LSTM: B=1024, T=512, F=64, H=128, 4H=512. out = h_T @ W_out^T + b_out.
// Strategy: 256 blocks x 4 batch rows. Recurrent+input GEMM fused as
// gates[4x512] = [h|x_t](K=192) @ [W_hh|W_ih]^T via bf16 MFMA 16x16x32,
// with weights held PERMANENTLY in registers as B-fragments (96 VGPR/lane).
// c-state fp32 in thread registers; h round-tripped through LDS as bf16.

#define T_SEQ   512
#define F_IN    64
#define H_DIM   128
#define G_DIM   512   // 4*H
#define BB      4     // batch rows per block
#define NTHREADS 512  // 8 waves
#define TILES   4     // 16-col N-tiles per wave (8 waves * 4 * 16 = 512 cols)
#define KSTEPS  6     // k = 0..127 from W_hh (h), 128..191 from W_ih (x)

typedef __bf16 bf16x8 __attribute__((ext_vector_type(8)));
typedef float  floatx4 __attribute__((ext_vector_type(4)));

__device__ __forceinline__ __bf16 to_bf16(float f) {
    __hip_bfloat16 h = __float2bfloat16(f);
    union { __hip_bfloat16 h; __bf16 b; } u;
    u.h = h;
    return u.b;
}

__device__ __forceinline__ float sigmoid_f(float x) {
    return 1.0f / (1.0f + __expf(-x));
}
__device__ __forceinline__ float tanh_f(float x) {
    float e2 = __expf(2.0f * x);
    return (e2 - 1.0f) / (e2 + 1.0f);
}

__global__ __launch_bounds__(NTHREADS, 2)
void lstm_fused_kernel(const float* __restrict__ x,
                       const float* __restrict__ W_ih,
                       const float* __restrict__ W_hh,
                       const float* __restrict__ b_ih,
                       const float* __restrict__ b_hh,
                       const float* __restrict__ W_out,
                       const float* __restrict__ b_out,
                       float* __restrict__ out)
{
    const int tid = threadIdx.x;
    const int w   = tid >> 6;    // wave id 0..7
    const int l   = tid & 63;    // lane
    const int lm  = l & 15;      // A-row (batch) / B-col (gate) within tile
    const int q   = l >> 4;      // quad 0..3 -> k = q*8 + j
    const int b0  = blockIdx.x * BB;

    // LDS. h/x rows padded +8 bf16 so the A-frag b128 reads are 2-way (free)
    // instead of 16-way bank conflicted (stride 128*2B puts all m on banks 0-3).
    __shared__ __align__(16) __bf16 h_sm[BB][136];
    __shared__ __align__(16) __bf16 x_sm[BB][72];
    __shared__ float gates_sm[BB][G_DIM];
    __shared__ float bias_sm[G_DIM];
    __shared__ float hf_sm[BB][H_DIM];

    // ---- Load persistent weight B-fragments (bf16), layout: elem j = W[n][kb+j],
    // n = lane&15 (+tile base), kb = kstep*32 + (lane>>4)*8. W rows: gate index n,
    // k<128 -> W_hh[n][k], k>=128 -> W_ih[n][k-128].
    bf16x8 wf[TILES][KSTEPS];
    #pragma unroll
    for (int i = 0; i < TILES; ++i) {
        const int n = w * 64 + i * 16 + lm;
        #pragma unroll
        for (int s = 0; s < KSTEPS; ++s) {
            const int kb = s * 32 + q * 8;
            const float* src = (kb < 128) ? (W_hh + (size_t)n * 128 + kb)
                                          : (W_ih + (size_t)n * 64 + (kb - 128));
            const float4 f0 = *reinterpret_cast<const float4*>(src);
            const float4 f1 = *reinterpret_cast<const float4*>(src + 4);
            bf16x8 v;
            v[0] = to_bf16(f0.x); v[1] = to_bf16(f0.y);
            v[2] = to_bf16(f0.z); v[3] = to_bf16(f0.w);
            v[4] = to_bf16(f1.x); v[5] = to_bf16(f1.y);
            v[6] = to_bf16(f1.z); v[7] = to_bf16(f1.w);
            wf[i][s] = v;
        }
    }

    // bias = b_ih + b_hh (added once per gate in elementwise phase)
    if (tid < G_DIM) bias_sm[tid] = b_ih[tid] + b_hh[tid];
    // h_0 = 0
    for (int idx = tid; idx < BB * 136; idx += NTHREADS)
        (&h_sm[0][0])[idx] = to_bf16(0.0f);

    float c    = 0.0f;   // thread-private cell state (fp32, persistent)
    float hval = 0.0f;
    const int b_ew = tid >> 7;   // elementwise mapping: thread -> (batch row, hidden j)
    const int j_ew = tid & 127;

    #pragma unroll 1
    for (int t = 0; t < T_SEQ; ++t) {
        // stage x_t -> bf16 LDS (coalesced: 64 consecutive floats per row)
        if (tid < 256) {
            const int m = tid >> 6, k = tid & 63;
            x_sm[m][k] = to_bf16(x[(size_t)(b0 + m) * T_SEQ * F_IN + (size_t)t * F_IN + k]);
        }
        __syncthreads();   // h_sm(t-1), x_sm(t) ready; gates_sm(t-1) consumed

        floatx4 acc[TILES];
        #pragma unroll
        for (int i = 0; i < TILES; ++i) acc[i] = floatx4{0.f, 0.f, 0.f, 0.f};

        // h-part: k-steps 0..3 (K=128)
        #pragma unroll
        for (int s = 0; s < 4; ++s) {
            bf16x8 a;
            #pragma unroll
            for (int jj = 0; jj < 8; ++jj) a[jj] = to_bf16(0.0f);
            if (lm < BB)
                a = *reinterpret_cast<const bf16x8*>(&h_sm[lm][s * 32 + q * 8]);
            #pragma unroll
            for (int i = 0; i < TILES; ++i)
                acc[i] = __builtin_amdgcn_mfma_f32_16x16x32_bf16(a, wf[i][s], acc[i], 0, 0, 0);
        }
        // x-part: k-steps 4..5 (K=64)
        #pragma unroll
        for (int s = 0; s < 2; ++s) {
            bf16x8 a;
            #pragma unroll
            for (int jj = 0; jj < 8; ++jj) a[jj] = to_bf16(0.0f);
            if (lm < BB)
                a = *reinterpret_cast<const bf16x8*>(&x_sm[lm][s * 32 + q * 8]);
            #pragma unroll
            for (int i = 0; i < TILES; ++i)
                acc[i] = __builtin_amdgcn_mfma_f32_16x16x32_bf16(a, wf[i][4 + s], acc[i], 0, 0, 0);
        }

        // C/D layout: col = lane&15, row = (lane>>4)*4 + reg. Real rows 0..3 live
        // in lanes 0..15 (q==0), regs 0..3.
        if (q == 0) {
            #pragma unroll
            for (int i = 0; i < TILES; ++i) {
                const int n = w * 64 + i * 16 + lm;
                #pragma unroll
                for (int r = 0; r < 4; ++r)
                    gates_sm[r][n] = acc[i][r];
            }
        }
        __syncthreads();   // gates ready

        // elementwise gate math; thread owns (b_ew, j_ew) for all t
        {
            const float gi = gates_sm[b_ew][j_ew]           + bias_sm[j_ew];
            const float gf = gates_sm[b_ew][H_DIM + j_ew]   + bias_sm[H_DIM + j_ew];
            const float gg = gates_sm[b_ew][2*H_DIM + j_ew] + bias_sm[2*H_DIM + j_ew];
            const float go = gates_sm[b_ew][3*H_DIM + j_ew] + bias_sm[3*H_DIM + j_ew];
            const float i_ = sigmoid_f(gi);
            const float f_ = sigmoid_f(gf);
            const float g_ = tanh_f(gg);
            const float o_ = sigmoid_f(go);
            c    = f_ * c + i_ * g_;
            hval = o_ * tanh_f(c);
            h_sm[b_ew][j_ew] = to_bf16(hval);
        }
    }

    // ---- final projection: out[b] = h_T @ W_out^T + b_out (fp32) ----
    hf_sm[b_ew][j_ew] = hval;
    __syncthreads();
    {
        const int m = b_ew, n = j_ew;
        float sum = b_out[n];
        const float* wrow = W_out + (size_t)n * H_DIM;
        #pragma unroll 8
        for (int jj = 0; jj < H_DIM; ++jj)
            sum += hf_sm[m][jj] * wrow[jj];
        out[(size_t)(b0 + m) * H_DIM + n] = sum;
    }
}

extern "C" void kernel_launch(void* const* d_in, const int* in_sizes, int n_in,
                              void* d_out, int out_size, void* d_ws, size_t ws_size,
                              hipStream_t stream) {
    const float* x     = (const float*)d_in[0];
    const float* W_ih  = (const float*)d_in[1];
    const float* W_hh  = (const float*)d_in[2];
    const float* b_ih  = (const float*)d_in[3];
    const float* b_hh  = (const float*)d_in[4];
    const float* W_out = (const float*)d_in[5];
    const float* b_out = (const float*)d_in[6];
    float* out = (float*)d_out;

    lstm_fused_kernel<<<dim3(1024 / BB), dim3(NTHREADS), 0, stream>>>(
        x, W_ih, W_hh, b_ih, b_hh, W_out, b_out, out);
}

// Round 2
// 677.345 us; speedup vs baseline: 1.2476x; 1.2476x over previous
//
#include <hip/hip_runtime.h>
#include <hip/hip_bf16.h>

// LSTM B=1024,T=512,F=64,H=128. 256 blocks x 4 batch rows, 8 waves.
// gates[4x512] = [h|x]K=192 @ [W_hh|W_ih]^T, bf16 MFMA 16x16x32, weights
// persistent in (A)GPR B-fragments. Gate-per-tile mapping: wave w tile i covers
// cols i*128 + w*16 + [0,16) -> all 4 gates of (row,j) in ONE lane's acc ->
// shfl redistribution, single barrier/step, no gates LDS. x A-frags direct
// from global, prefetched 2 steps ahead; x-MFMAs for t+1 overlap step t's EW.

#define T_SEQ   512
#define F_IN    64
#define H_DIM   128
#define BB      4
#define NTHREADS 512
#define NT      4    // tiles/wave = 4 gates
#define KH      4    // h k-steps (K=128)
#define KX      2    // x k-steps (K=64)

typedef __bf16 bf16x8 __attribute__((ext_vector_type(8)));
typedef float  floatx4 __attribute__((ext_vector_type(4)));

__device__ __forceinline__ __bf16 to_bf16(float f) {
    union { __hip_bfloat16 h; __bf16 b; } u;
    u.h = __float2bfloat16(f);
    return u.b;
}
__device__ __forceinline__ float fast_rcp(float x) { return __builtin_amdgcn_rcpf(x); }
__device__ __forceinline__ float sigmoid_f(float x) {
    return fast_rcp(1.0f + __expf(-x));
}
__device__ __forceinline__ float tanh_f(float x) {
    float e2 = __expf(2.0f * x);
    return (e2 - 1.0f) * fast_rcp(e2 + 1.0f);
}

__global__ __launch_bounds__(NTHREADS, 2)
void lstm_fused_kernel(const float* __restrict__ x,
                       const float* __restrict__ W_ih,
                       const float* __restrict__ W_hh,
                       const float* __restrict__ b_ih,
                       const float* __restrict__ b_hh,
                       const float* __restrict__ W_out,
                       const float* __restrict__ b_out,
                       float* __restrict__ out)
{
    const int tid = threadIdx.x;
    const int w   = tid >> 6;        // wave 0..7
    const int l   = tid & 63;
    const int lm  = l & 15;          // A row (batch) / B col-within-tile
    const int q   = l >> 4;          // quad: A k-sub / D row group / EW batch row
    const int b0  = blockIdx.x * BB;

    // h_sm: 16 rows (rows 4..15 stay zero forever -> unconditional A-frag reads,
    // their D rows are never extracted). +8 pad keeps b128 reads conflict-free.
    __shared__ __align__(16) __bf16 h_sm[16][136];
    __shared__ float hf_sm[BB][H_DIM];

    // ---- persistent weight B-frags: elem j = W[n][kb+j], n = i*128 + w*16 + lm,
    // kb = s*32 + q*8; k<128 -> W_hh, k>=128 -> W_ih. Plus bias per tile.
    bf16x8 wf[NT][KH + KX];
    float  biasf[NT];
    #pragma unroll
    for (int i = 0; i < NT; ++i) {
        const int n = i * H_DIM + w * 16 + lm;
        biasf[i] = b_ih[n] + b_hh[n];
        #pragma unroll
        for (int s = 0; s < KH + KX; ++s) {
            const int kb = s * 32 + q * 8;
            const float* src = (kb < 128) ? (W_hh + (size_t)n * 128 + kb)
                                          : (W_ih + (size_t)n * 64 + (kb - 128));
            const float4 f0 = *reinterpret_cast<const float4*>(src);
            const float4 f1 = *reinterpret_cast<const float4*>(src + 4);
            bf16x8 v;
            v[0] = to_bf16(f0.x); v[1] = to_bf16(f0.y);
            v[2] = to_bf16(f0.z); v[3] = to_bf16(f0.w);
            v[4] = to_bf16(f1.x); v[5] = to_bf16(f1.y);
            v[6] = to_bf16(f1.z); v[7] = to_bf16(f1.w);
            wf[i][s] = v;
        }
    }

    // zero h_sm once (incl. dummy rows 4..15)
    for (int idx = tid; idx < 16 * 136; idx += NTHREADS)
        (&h_sm[0][0])[idx] = to_bf16(0.0f);

    // x A-frag base: row-in-tile = lm, real rows lm<4, clamp rest to valid mem
    const float* xrow = x + (size_t)(b0 + (lm & 3)) * T_SEQ * F_IN + q * 8;

    float4 xf[KX][2];
    // load x(0)
    #pragma unroll
    for (int sx = 0; sx < KX; ++sx) {
        xf[sx][0] = *reinterpret_cast<const float4*>(xrow + sx * 32);
        xf[sx][1] = *reinterpret_cast<const float4*>(xrow + sx * 32 + 4);
    }

    floatx4 acc[NT];
    // seed acc with bias + x-part of step 0
    #pragma unroll
    for (int i = 0; i < NT; ++i)
        acc[i] = floatx4{biasf[i], biasf[i], biasf[i], biasf[i]};
    #pragma unroll
    for (int sx = 0; sx < KX; ++sx) {
        bf16x8 ax;
        ax[0] = to_bf16(xf[sx][0].x); ax[1] = to_bf16(xf[sx][0].y);
        ax[2] = to_bf16(xf[sx][0].z); ax[3] = to_bf16(xf[sx][0].w);
        ax[4] = to_bf16(xf[sx][1].x); ax[5] = to_bf16(xf[sx][1].y);
        ax[6] = to_bf16(xf[sx][1].z); ax[7] = to_bf16(xf[sx][1].w);
        #pragma unroll
        for (int i = 0; i < NT; ++i)
            acc[i] = __builtin_amdgcn_mfma_f32_16x16x32_bf16(ax, wf[i][KH + sx], acc[i], 0, 0, 0);
    }
    // prefetch x(1)
    #pragma unroll
    for (int sx = 0; sx < KX; ++sx) {
        xf[sx][0] = *reinterpret_cast<const float4*>(xrow + 1 * F_IN + sx * 32);
        xf[sx][1] = *reinterpret_cast<const float4*>(xrow + 1 * F_IN + sx * 32 + 4);
    }

    float c    = 0.0f;   // cell state for (row=q, j=w*16+lm), fp32, persistent
    float hval = 0.0f;
    const int jcol = w * 16 + lm;

    #pragma unroll 1
    for (int t = 0; t < T_SEQ; ++t) {
        __syncthreads();   // h_sm(t-1) visible

        // h-part MFMAs: acc already holds bias + x-part(t)
        bf16x8 ah[KH];
        #pragma unroll
        for (int s = 0; s < KH; ++s)
            ah[s] = *reinterpret_cast<const bf16x8*>(&h_sm[lm][s * 32 + q * 8]);
        #pragma unroll
        for (int s = 0; s < KH; ++s) {
            #pragma unroll
            for (int i = 0; i < NT; ++i)
                acc[i] = __builtin_amdgcn_mfma_f32_16x16x32_bf16(ah[s], wf[i][s], acc[i], 0, 0, 0);
        }

        // redistribute: lane l takes batch row r=q from source lane lm's reg q.
        // src lane lm (quad 0) holds D rows 0..3 in regs 0..3 for col jcol.
        float gate[4];
        #pragma unroll
        for (int g = 0; g < 4; ++g) {
            const float v0 = __shfl(acc[g][0], lm);
            const float v1 = __shfl(acc[g][1], lm);
            const float v2 = __shfl(acc[g][2], lm);
            const float v3 = __shfl(acc[g][3], lm);
            gate[g] = (q == 0) ? v0 : (q == 1) ? v1 : (q == 2) ? v2 : v3;
        }

        // re-seed acc with bias + x-part(t+1) using prefetched xf; then
        // prefetch x(t+2). Independent of EW -> fills the EW/barrier shadow.
        #pragma unroll
        for (int i = 0; i < NT; ++i)
            acc[i] = floatx4{biasf[i], biasf[i], biasf[i], biasf[i]};
        #pragma unroll
        for (int sx = 0; sx < KX; ++sx) {
            bf16x8 ax;
            ax[0] = to_bf16(xf[sx][0].x); ax[1] = to_bf16(xf[sx][0].y);
            ax[2] = to_bf16(xf[sx][0].z); ax[3] = to_bf16(xf[sx][0].w);
            ax[4] = to_bf16(xf[sx][1].x); ax[5] = to_bf16(xf[sx][1].y);
            ax[6] = to_bf16(xf[sx][1].z); ax[7] = to_bf16(xf[sx][1].w);
            #pragma unroll
            for (int i = 0; i < NT; ++i)
                acc[i] = __builtin_amdgcn_mfma_f32_16x16x32_bf16(ax, wf[i][KH + sx], acc[i], 0, 0, 0);
        }
        {
            const int t2 = (t + 2 < T_SEQ) ? t + 2 : T_SEQ - 1;
            #pragma unroll
            for (int sx = 0; sx < KX; ++sx) {
                xf[sx][0] = *reinterpret_cast<const float4*>(xrow + (size_t)t2 * F_IN + sx * 32);
                xf[sx][1] = *reinterpret_cast<const float4*>(xrow + (size_t)t2 * F_IN + sx * 32 + 4);
            }
        }

        // elementwise gate math for (row=q, col=jcol); all lanes active
        {
            const float i_ = sigmoid_f(gate[0]);
            const float f_ = sigmoid_f(gate[1]);
            const float g_ = tanh_f(gate[2]);
            const float o_ = sigmoid_f(gate[3]);
            c    = f_ * c + i_ * g_;
            hval = o_ * tanh_f(c);
            h_sm[q][jcol] = to_bf16(hval);
        }
    }

    // ---- projection: out[b] = h_T @ W_out^T + b_out ----
    hf_sm[q][jcol] = hval;
    __syncthreads();
    {
        const int m = tid >> 7, n = tid & 127;
        float sum = b_out[n];
        const float* wrow = W_out + (size_t)n * H_DIM;
        #pragma unroll 8
        for (int jj = 0; jj < H_DIM; ++jj)
            sum += hf_sm[m][jj] * wrow[jj];
        out[(size_t)(b0 + m) * H_DIM + n] = sum;
    }
}

extern "C" void kernel_launch(void* const* d_in, const int* in_sizes, int n_in,
                              void* d_out, int out_size, void* d_ws, size_t ws_size,
                              hipStream_t stream) {
    const float* x     = (const float*)d_in[0];
    const float* W_ih  = (const float*)d_in[1];
    const float* W_hh  = (const float*)d_in[2];
    const float* b_ih  = (const float*)d_in[3];
    const float* b_hh  = (const float*)d_in[4];
    const float* W_out = (const float*)d_in[5];
    const float* b_out = (const float*)d_in[6];
    float* out = (float*)d_out;

    lstm_fused_kernel<<<dim3(1024 / BB), dim3(NTHREADS), 0, stream>>>(
        x, W_ih, W_hh, b_ih, b_hh, W_out, b_out, out);
}

// Round 3
// 623.919 us; speedup vs baseline: 1.3545x; 1.0856x over previous
//
#include <hip/hip_runtime.h>
#include <hip/hip_bf16.h>

// LSTM B=1024,T=512,F=64,H=128. 256 blocks x 4 batch rows, 8 waves.
// gates[4x512] = [h|x]K=192 @ [W_hh|W_ih]^T, bf16 MFMA 16x16x32, weights
// persistent in registers. REPLICATED-M: A rows 0..15 = batch rows (m&3), so
// D reg r = batch row r in EVERY lane -> gate select is 3 cndmask (no shfl,
// no gates LDS). h_sm double-buffered (read t-1 / write t race fixed), rows
// padded to 144 bf16 (stride=72 dw = 8 mod 32 -> <=2-way banks). x prefetch
// issued at TOP of body so the vmcnt(0)-before-barrier drain is covered by a
// full body. acc seeded via MFMA with persistent zero-C (no re-seed movs);
// bias folded into gate select.

#define T_SEQ   512
#define F_IN    64
#define H_DIM   128
#define BB      4
#define NTHREADS 512
#define NT      4    // tiles/wave = 4 gates (gate g cols g*128 + w*16 + lm)
#define KH      4    // h k-steps (K=128)
#define KX      2    // x k-steps (K=64)
#define HPAD    144  // h row stride in bf16 (72 dwords == 8 mod 32)

typedef __bf16 bf16x8 __attribute__((ext_vector_type(8)));
typedef float  floatx4 __attribute__((ext_vector_type(4)));

__device__ __forceinline__ __bf16 to_bf16(float f) {
    union { __hip_bfloat16 h; __bf16 b; } u;
    u.h = __float2bfloat16(f);
    return u.b;
}
__device__ __forceinline__ float fast_rcp(float x) { return __builtin_amdgcn_rcpf(x); }
__device__ __forceinline__ float sigmoid_f(float x) {
    return fast_rcp(1.0f + __expf(-x));
}
__device__ __forceinline__ float tanh_f(float x) {
    float e2 = __expf(2.0f * x);
    return (e2 - 1.0f) * fast_rcp(e2 + 1.0f);
}

__global__ __launch_bounds__(NTHREADS, 2)
void lstm_fused_kernel(const float* __restrict__ x,
                       const float* __restrict__ W_ih,
                       const float* __restrict__ W_hh,
                       const float* __restrict__ b_ih,
                       const float* __restrict__ b_hh,
                       const float* __restrict__ W_out,
                       const float* __restrict__ b_out,
                       float* __restrict__ out)
{
    const int tid = threadIdx.x;
    const int w   = tid >> 6;        // wave 0..7
    const int l   = tid & 63;
    const int lm  = l & 15;          // B col-within-tile; A row (replicated lm&3)
    const int q   = l >> 4;          // quad: A k-sub; EW batch row
    const int b0  = blockIdx.x * BB;
    const int jcol = w * 16 + lm;    // hidden index this lane EWs (row q)

    __shared__ __align__(16) __bf16 h_sm[2][BB][HPAD];  // double-buffered h
    __shared__ float hf_sm[BB][H_DIM];

    // ---- persistent weight B-frags: elem j = W[n][kb+j], n = g*128 + jcol,
    // kb = s*32 + q*8; k<128 -> W_hh, k>=128 -> W_ih. bias per gate.
    bf16x8 wf[NT][KH + KX];
    float  biasf[NT];
    #pragma unroll
    for (int g = 0; g < NT; ++g) {
        const int n = g * H_DIM + jcol;
        biasf[g] = b_ih[n] + b_hh[n];
        #pragma unroll
        for (int s = 0; s < KH + KX; ++s) {
            const int kb = s * 32 + q * 8;
            const float* src = (kb < 128) ? (W_hh + (size_t)n * 128 + kb)
                                          : (W_ih + (size_t)n * 64 + (kb - 128));
            const float4 f0 = *reinterpret_cast<const float4*>(src);
            const float4 f1 = *reinterpret_cast<const float4*>(src + 4);
            bf16x8 v;
            v[0] = to_bf16(f0.x); v[1] = to_bf16(f0.y);
            v[2] = to_bf16(f0.z); v[3] = to_bf16(f0.w);
            v[4] = to_bf16(f1.x); v[5] = to_bf16(f1.y);
            v[6] = to_bf16(f1.z); v[7] = to_bf16(f1.w);
            wf[g][s] = v;
        }
    }

    // zero both h buffers
    for (int idx = tid; idx < 2 * BB * HPAD; idx += NTHREADS)
        (&h_sm[0][0][0])[idx] = to_bf16(0.0f);

    const floatx4 zero4 = {0.f, 0.f, 0.f, 0.f};

    // x A-frag source: row lm&3 (replicated), k-sub q*8
    const float* xrow = x + (size_t)(b0 + (lm & 3)) * T_SEQ * F_IN + q * 8;

    // ---- pre-loop: acc = x-part(0); xf[0] <- x(1)
    floatx4 acc[NT];
    {
        float4 x0[KX][2];
        #pragma unroll
        for (int sx = 0; sx < KX; ++sx) {
            x0[sx][0] = *reinterpret_cast<const float4*>(xrow + sx * 32);
            x0[sx][1] = *reinterpret_cast<const float4*>(xrow + sx * 32 + 4);
        }
        #pragma unroll
        for (int sx = 0; sx < KX; ++sx) {
            bf16x8 ax;
            ax[0] = to_bf16(x0[sx][0].x); ax[1] = to_bf16(x0[sx][0].y);
            ax[2] = to_bf16(x0[sx][0].z); ax[3] = to_bf16(x0[sx][0].w);
            ax[4] = to_bf16(x0[sx][1].x); ax[5] = to_bf16(x0[sx][1].y);
            ax[6] = to_bf16(x0[sx][1].z); ax[7] = to_bf16(x0[sx][1].w);
            #pragma unroll
            for (int g = 0; g < NT; ++g)
                acc[g] = __builtin_amdgcn_mfma_f32_16x16x32_bf16(
                    ax, wf[g][KH + sx], (sx == 0) ? zero4 : acc[g], 0, 0, 0);
        }
    }
    float4 xf[2][KX][2];
    #pragma unroll
    for (int sx = 0; sx < KX; ++sx) {
        xf[0][sx][0] = *reinterpret_cast<const float4*>(xrow + F_IN + sx * 32);
        xf[0][sx][1] = *reinterpret_cast<const float4*>(xrow + F_IN + sx * 32 + 4);
    }

    float c    = 0.0f;   // cell state for (row=q, j=jcol), fp32, persistent
    float hval = 0.0f;

    #pragma unroll 1
    for (int t = 0; t < T_SEQ; t += 2) {
        #pragma unroll
        for (int p = 0; p < 2; ++p) {
            const int tt = t + p;     // step index; read h buf (tt&1), write (tt&1)^1
            __syncthreads();          // h(tt-1) visible; drains in-flight x loads

            // issue x(tt+2) loads NOW -> full body of latency before next drain
            {
                const int t2 = (tt + 2 < T_SEQ) ? tt + 2 : T_SEQ - 1;
                const float* xp = xrow + (size_t)t2 * F_IN;
                #pragma unroll
                for (int sx = 0; sx < KX; ++sx) {
                    xf[p ^ 1][sx][0] = *reinterpret_cast<const float4*>(xp + sx * 32);
                    xf[p ^ 1][sx][1] = *reinterpret_cast<const float4*>(xp + sx * 32 + 4);
                }
            }

            // h-part MFMAs onto acc (holds x-part(tt))
            const __bf16* hrow = &h_sm[p][lm & 3][q * 8];
            bf16x8 ah[KH];
            #pragma unroll
            for (int s = 0; s < KH; ++s)
                ah[s] = *reinterpret_cast<const bf16x8*>(hrow + s * 32);
            #pragma unroll
            for (int s = 0; s < KH; ++s) {
                #pragma unroll
                for (int g = 0; g < NT; ++g)
                    acc[g] = __builtin_amdgcn_mfma_f32_16x16x32_bf16(ah[s], wf[g][s], acc[g], 0, 0, 0);
            }

            // D reg r = batch row r (replicated M). Lane owns (row q, col jcol):
            float gate[4];
            #pragma unroll
            for (int g = 0; g < NT; ++g)
                gate[g] = ((q == 0) ? acc[g][0] : (q == 1) ? acc[g][1]
                           : (q == 2) ? acc[g][2] : acc[g][3]) + biasf[g];

            // x-part(tt+1) into acc with zero-C (no reseed movs); data arrived
            // (drained by this step's barrier)
            #pragma unroll
            for (int sx = 0; sx < KX; ++sx) {
                bf16x8 ax;
                ax[0] = to_bf16(xf[p][sx][0].x); ax[1] = to_bf16(xf[p][sx][0].y);
                ax[2] = to_bf16(xf[p][sx][0].z); ax[3] = to_bf16(xf[p][sx][0].w);
                ax[4] = to_bf16(xf[p][sx][1].x); ax[5] = to_bf16(xf[p][sx][1].y);
                ax[6] = to_bf16(xf[p][sx][1].z); ax[7] = to_bf16(xf[p][sx][1].w);
                #pragma unroll
                for (int g = 0; g < NT; ++g)
                    acc[g] = __builtin_amdgcn_mfma_f32_16x16x32_bf16(
                        ax, wf[g][KH + sx], (sx == 0) ? zero4 : acc[g], 0, 0, 0);
            }

            // elementwise for (row q, col jcol)
            {
                const float i_ = sigmoid_f(gate[0]);
                const float f_ = sigmoid_f(gate[1]);
                const float g_ = tanh_f(gate[2]);
                const float o_ = sigmoid_f(gate[3]);
                c    = f_ * c + i_ * g_;
                hval = o_ * tanh_f(c);
                h_sm[p ^ 1][q][jcol] = to_bf16(hval);
            }
        }
    }

    // ---- projection: out[b] = h_T @ W_out^T + b_out ----
    hf_sm[q][jcol] = hval;
    __syncthreads();
    {
        const int m = tid >> 7, n = tid & 127;
        float sum = b_out[n];
        const float* wrow = W_out + (size_t)n * H_DIM;
        #pragma unroll 8
        for (int jj = 0; jj < H_DIM; ++jj)
            sum += hf_sm[m][jj] * wrow[jj];
        out[(size_t)(b0 + m) * H_DIM + n] = sum;
    }
}

extern "C" void kernel_launch(void* const* d_in, const int* in_sizes, int n_in,
                              void* d_out, int out_size, void* d_ws, size_t ws_size,
                              hipStream_t stream) {
    const float* x     = (const float*)d_in[0];
    const float* W_ih  = (const float*)d_in[1];
    const float* W_hh  = (const float*)d_in[2];
    const float* b_ih  = (const float*)d_in[3];
    const float* b_hh  = (const float*)d_in[4];
    const float* W_out = (const float*)d_in[5];
    const float* b_out = (const float*)d_in[6];
    float* out = (float*)d_out;

    lstm_fused_kernel<<<dim3(1024 / BB), dim3(NTHREADS), 0, stream>>>(
        x, W_ih, W_hh, b_ih, b_hh, W_out, b_out, out);
}

// Round 4
// 522.284 us; speedup vs baseline: 1.6181x; 1.1946x over previous
//
#include <hip/hip_runtime.h>
#include <hip/hip_bf16.h>

// LSTM B=1024,T=512,F=64,H=128. 256 blocks x 4 batch rows, 8 waves, 1/CU.
// h-GEMM: replicated-M bf16 MFMA 16x16x32 (D reg r = batch row r in every
// lane -> gate select = cndmask, no shfl/LDS). x-GEMM: batched 4 timesteps
// into the M dim (A row m = batchrow*4 + t_sub) -> lane (q,jcol) receives
// xg[q][t+reg][gate,jcol] in its OWN acc regs; 8 MFMAs + 8 pk-cvts per 4
// steps (was 32 + 64). All f32->bf16 via 2-op round-half-up (no software
// RNE). Weights persistent in registers (96 VGPR). h_sm double-buffered,
// HPAD=144 keeps LDS 2-way max. x loads for chunk C+2 issued inside step
// r=0 body -> a full step of latency before the vmcnt(0) barrier drain.

#define T_SEQ   512
#define F_IN    64
#define H_DIM   128
#define BB      4
#define NTHREADS 512
#define NG      4    // gate tiles per wave
#define KH      4    // h k-steps (K=128)
#define KX      2    // x k-steps (K=64)
#define CH      4    // timestep chunk for batched x-GEMM
#define HPAD    144

typedef __bf16 bf16x8 __attribute__((ext_vector_type(8)));
typedef float  floatx4 __attribute__((ext_vector_type(4)));

__device__ __forceinline__ __bf16 bf16_rhu(float f) {
    unsigned u = __builtin_bit_cast(unsigned, f) + 0x8000u;
    unsigned short s = (unsigned short)(u >> 16);
    return __builtin_bit_cast(__bf16, s);
}
__device__ __forceinline__ unsigned pk2_bf16(float a, float b) {
    unsigned ua = __builtin_bit_cast(unsigned, a);
    unsigned ub = __builtin_bit_cast(unsigned, b);
    return ((ua + 0x8000u) >> 16) | ((ub + 0x8000u) & 0xFFFF0000u);
}
__device__ __forceinline__ bf16x8 pack_frag(const float4 lo, const float4 hi) {
    union { unsigned u[4]; bf16x8 v; } r;
    r.u[0] = pk2_bf16(lo.x, lo.y);
    r.u[1] = pk2_bf16(lo.z, lo.w);
    r.u[2] = pk2_bf16(hi.x, hi.y);
    r.u[3] = pk2_bf16(hi.z, hi.w);
    return r.v;
}
__device__ __forceinline__ __bf16 to_bf16(float f) {   // RNE, prologue only
    union { __hip_bfloat16 h; __bf16 b; } u;
    u.h = __float2bfloat16(f);
    return u.b;
}
__device__ __forceinline__ float fast_rcp(float x) { return __builtin_amdgcn_rcpf(x); }
__device__ __forceinline__ float sigmoid_f(float x) { return fast_rcp(1.0f + __expf(-x)); }
__device__ __forceinline__ float tanh_f(float x) {
    float e2 = __expf(2.0f * x);
    return (e2 - 1.0f) * fast_rcp(e2 + 1.0f);
}

__global__ __launch_bounds__(NTHREADS, 2)
void lstm_fused_kernel(const float* __restrict__ x,
                       const float* __restrict__ W_ih,
                       const float* __restrict__ W_hh,
                       const float* __restrict__ b_ih,
                       const float* __restrict__ b_hh,
                       const float* __restrict__ W_out,
                       const float* __restrict__ b_out,
                       float* __restrict__ out)
{
    const int tid = threadIdx.x;
    const int w   = tid >> 6;
    const int l   = tid & 63;
    const int lm  = l & 15;        // A row within tile; B col-within-tile
    const int q   = l >> 4;        // quad: A k-sub; D row group; EW batch row
    const int b0  = blockIdx.x * BB;
    const int jcol = w * 16 + lm;  // hidden col this lane EWs (batch row q)

    __shared__ __align__(16) __bf16 h_sm[2][BB][HPAD];
    __shared__ float hf_sm[BB][H_DIM];

    // persistent weight B-frags: elem j = W[n][kb+j], n = g*128 + jcol,
    // kb = s*32 + q*8; s<4 -> W_hh, s>=4 -> W_ih(k-128). bias per gate.
    bf16x8 wf[NG][KH + KX];
    float  biasf[NG];
    #pragma unroll
    for (int g = 0; g < NG; ++g) {
        const int n = g * H_DIM + jcol;
        biasf[g] = b_ih[n] + b_hh[n];
        #pragma unroll
        for (int s = 0; s < KH + KX; ++s) {
            const int kb = s * 32 + q * 8;
            const float* src = (kb < 128) ? (W_hh + (size_t)n * 128 + kb)
                                          : (W_ih + (size_t)n * 64 + (kb - 128));
            const float4 f0 = *reinterpret_cast<const float4*>(src);
            const float4 f1 = *reinterpret_cast<const float4*>(src + 4);
            bf16x8 v;
            v[0] = to_bf16(f0.x); v[1] = to_bf16(f0.y);
            v[2] = to_bf16(f0.z); v[3] = to_bf16(f0.w);
            v[4] = to_bf16(f1.x); v[5] = to_bf16(f1.y);
            v[6] = to_bf16(f1.z); v[7] = to_bf16(f1.w);
            wf[g][s] = v;
        }
    }

    for (int idx = tid; idx < 2 * BB * HPAD; idx += NTHREADS)
        (&h_sm[0][0][0])[idx] = to_bf16(0.0f);

    const floatx4 zero4 = {0.f, 0.f, 0.f, 0.f};

    // x-GEMM A source: A row m = batchrow*4 + t_sub -> this lane (row lm)
    // reads x[b0 + (lm>>2)][tchunk + (lm&3)][q*8 + sx*32 .. +8]
    const float* xga = x + ((size_t)(b0 + (lm >> 2)) * T_SEQ + (lm & 3)) * F_IN + q * 8;

    // prologue: xg_cur = xg(chunk 0); xld = x(chunk 1)
    floatx4 xg_cur[NG];
    {
        const float4 a0 = *reinterpret_cast<const float4*>(xga);
        const float4 a1 = *reinterpret_cast<const float4*>(xga + 4);
        const float4 a2 = *reinterpret_cast<const float4*>(xga + 32);
        const float4 a3 = *reinterpret_cast<const float4*>(xga + 36);
        const bf16x8 ax0 = pack_frag(a0, a1);
        const bf16x8 ax1 = pack_frag(a2, a3);
        #pragma unroll
        for (int g = 0; g < NG; ++g) {
            xg_cur[g] = __builtin_amdgcn_mfma_f32_16x16x32_bf16(ax0, wf[g][KH + 0], zero4, 0, 0, 0);
            xg_cur[g] = __builtin_amdgcn_mfma_f32_16x16x32_bf16(ax1, wf[g][KH + 1], xg_cur[g], 0, 0, 0);
        }
    }
    float4 xld[4];
    {
        const float* xp = xga + CH * F_IN;
        xld[0] = *reinterpret_cast<const float4*>(xp);
        xld[1] = *reinterpret_cast<const float4*>(xp + 4);
        xld[2] = *reinterpret_cast<const float4*>(xp + 32);
        xld[3] = *reinterpret_cast<const float4*>(xp + 36);
    }

    float c = 0.0f, hval = 0.0f;

    #pragma unroll 1
    for (int tc = 0; tc < T_SEQ; tc += CH) {
        floatx4 xg_next[NG];
        float4  xnew[4];
        #pragma unroll
        for (int r = 0; r < CH; ++r) {
            __syncthreads();   // h(tc+r-1) visible; drains in-flight x loads

            if (r == 0) {
                // loads for chunk C+2 (clamped) — issued after this barrier,
                // drained at next step's barrier: one full step of cover
                const int tn = (tc + 2 * CH < T_SEQ) ? (tc + 2 * CH) : (T_SEQ - CH);
                const float* xp = xga + (size_t)tn * F_IN;
                xnew[0] = *reinterpret_cast<const float4*>(xp);
                xnew[1] = *reinterpret_cast<const float4*>(xp + 4);
                xnew[2] = *reinterpret_cast<const float4*>(xp + 32);
                xnew[3] = *reinterpret_cast<const float4*>(xp + 36);
                // xg_next = xg(chunk C+1) from xld
                const bf16x8 ax0 = pack_frag(xld[0], xld[1]);
                const bf16x8 ax1 = pack_frag(xld[2], xld[3]);
                #pragma unroll
                for (int g = 0; g < NG; ++g) {
                    xg_next[g] = __builtin_amdgcn_mfma_f32_16x16x32_bf16(ax0, wf[g][KH + 0], zero4, 0, 0, 0);
                    xg_next[g] = __builtin_amdgcn_mfma_f32_16x16x32_bf16(ax1, wf[g][KH + 1], xg_next[g], 0, 0, 0);
                }
            }

            // h-part MFMAs (replicated-M A from LDS)
            const int p = r & 1;                       // read buf (tt&1)
            const __bf16* hrow = &h_sm[p][lm & 3][q * 8];
            bf16x8 ah[KH];
            #pragma unroll
            for (int s = 0; s < KH; ++s)
                ah[s] = *reinterpret_cast<const bf16x8*>(hrow + s * 32);
            floatx4 hacc[NG];
            #pragma unroll
            for (int s = 0; s < KH; ++s) {
                #pragma unroll
                for (int g = 0; g < NG; ++g)
                    hacc[g] = __builtin_amdgcn_mfma_f32_16x16x32_bf16(
                        ah[s], wf[g][s], (s == 0) ? zero4 : hacc[g], 0, 0, 0);
            }

            // lane owns (batch row q, col jcol); D reg r' = batch row r'
            float gate[NG];
            #pragma unroll
            for (int g = 0; g < NG; ++g) {
                const float hsel = (q == 0) ? hacc[g][0] : (q == 1) ? hacc[g][1]
                                 : (q == 2) ? hacc[g][2] : hacc[g][3];
                gate[g] = hsel + xg_cur[g][r] + biasf[g];
            }
            const float i_ = sigmoid_f(gate[0]);
            const float f_ = sigmoid_f(gate[1]);
            const float g_ = tanh_f(gate[2]);
            const float o_ = sigmoid_f(gate[3]);
            c    = f_ * c + i_ * g_;
            hval = o_ * tanh_f(c);
            h_sm[p ^ 1][q][jcol] = bf16_rhu(hval);
        }
        #pragma unroll
        for (int g = 0; g < NG; ++g) xg_cur[g] = xg_next[g];
        #pragma unroll
        for (int i = 0; i < 4; ++i)  xld[i] = xnew[i];
    }

    // projection: out[b] = h_T @ W_out^T + b_out
    hf_sm[q][jcol] = hval;
    __syncthreads();
    {
        const int m = tid >> 7, n = tid & 127;
        float sum = b_out[n];
        const float* wrow = W_out + (size_t)n * H_DIM;
        #pragma unroll 8
        for (int jj = 0; jj < H_DIM; ++jj)
            sum += hf_sm[m][jj] * wrow[jj];
        out[(size_t)(b0 + m) * H_DIM + n] = sum;
    }
}

extern "C" void kernel_launch(void* const* d_in, const int* in_sizes, int n_in,
                              void* d_out, int out_size, void* d_ws, size_t ws_size,
                              hipStream_t stream) {
    const float* x     = (const float*)d_in[0];
    const float* W_ih  = (const float*)d_in[1];
    const float* W_hh  = (const float*)d_in[2];
    const float* b_ih  = (const float*)d_in[3];
    const float* b_hh  = (const float*)d_in[4];
    const float* W_out = (const float*)d_in[5];
    const float* b_out = (const float*)d_in[6];
    float* out = (float*)d_out;

    lstm_fused_kernel<<<dim3(1024 / BB), dim3(NTHREADS), 0, stream>>>(
        x, W_ih, W_hh, b_ih, b_hh, W_out, b_out, out);
}